// Round 1
// baseline (444.912 us; speedup 1.0000x reference)
//
#include <hip/hip_runtime.h>
#include <math.h>

#define Bb 2
#define Nn 2048
#define DIMM 512
#define Hh 8
#define DHd 64
#define SCALE 0.125f

typedef __bf16 bf16;
typedef __bf16 bf16x8 __attribute__((ext_vector_type(8)));
typedef float f32x4 __attribute__((ext_vector_type(4)));

// workspace byte offsets
#define WS_XB   0u            // x bf16:   4096*512*2          = 4 MB
#define WS_WB   4194304u      // Wq,Wk,Wv,Wo bf16: 4*512*512*2 = 2 MB
#define WS_Q    6291456u      // q  [b][h][n][d] bf16          = 4 MB
#define WS_K    10485760u     // k  [b][h][n][d] bf16          = 4 MB
#define WS_VT   14680064u     // vT [b][h][d][n] bf16          = 4 MB
#define WS_AT   18874368u     // attn out [b][n][h*64+d] bf16  = 4 MB

// ---------------- Kernel A: fp32 -> bf16 pack ----------------
__global__ __launch_bounds__(256) void convert_kernel(
    const float* __restrict__ x, const float* __restrict__ wq,
    const float* __restrict__ wk, const float* __restrict__ wv,
    const float* __restrict__ wo, bf16* __restrict__ xb, bf16* __restrict__ wb) {
  int i = blockIdx.x * 256 + threadIdx.x;  // float4 index; total 786432
  const float4* src; bf16* dst; int off;
  if (i < 524288) { src = (const float4*)x; dst = xb; off = i; }
  else {
    int j = i - 524288;
    int wsel = j >> 16; off = j & 65535;
    const float* wl = wsel == 0 ? wq : wsel == 1 ? wk : wsel == 2 ? wv : wo;
    src = (const float4*)wl; dst = wb + (wsel << 18);
  }
  float4 v = src[off];
  union { bf16 h[4]; uint2 u; } tmp;
  tmp.h[0] = (bf16)v.x; tmp.h[1] = (bf16)v.y;
  tmp.h[2] = (bf16)v.z; tmp.h[3] = (bf16)v.w;
  ((uint2*)dst)[off] = tmp.u;
}

// ---------------- Kernel B: QKV projection GEMM ----------------
// C[m][n] = sum_k xb[m][k]*wb[n][k] + bias ; n in [0,1536) = {q|k|v}
__global__ __launch_bounds__(256) void qkv_gemm(
    const bf16* __restrict__ xb, const bf16* __restrict__ wb,
    const float* __restrict__ bq, const float* __restrict__ bk,
    const float* __restrict__ bv, bf16* __restrict__ qws,
    bf16* __restrict__ kws, bf16* __restrict__ vtws) {
  __shared__ bf16 Al[128 * 40];  // stride 40 (pad 8) -> 80B rows, 16B aligned
  __shared__ bf16 Bl[128 * 40];
  int t = threadIdx.x;
  int m0 = (blockIdx.x & 31) << 7;
  int n0 = (blockIdx.x >> 5) << 7;
  int lane = t & 63, w = t >> 6;
  int quad = lane >> 4, col = lane & 15;
  int mblk = (w >> 1) * 64, nblk = (w & 1) * 64;
  f32x4 acc[4][4] = {};
  for (int k0 = 0; k0 < 512; k0 += 32) {
    __syncthreads();
    for (int pass = 0; pass < 2; ++pass) {
      int c = t + (pass << 8);
      int row = c >> 2, part = c & 3;
      *(uint4*)&Al[row * 40 + part * 8] =
          *(const uint4*)&xb[(m0 + row) * 512 + k0 + part * 8];
      *(uint4*)&Bl[row * 40 + part * 8] =
          *(const uint4*)&wb[(n0 + row) * 512 + k0 + part * 8];
    }
    __syncthreads();
    bf16x8 af[4], bfv[4];
    for (int i = 0; i < 4; i++)
      af[i] = *(const bf16x8*)&Al[(mblk + i * 16 + col) * 40 + quad * 8];
    for (int i = 0; i < 4; i++)
      bfv[i] = *(const bf16x8*)&Bl[(nblk + i * 16 + col) * 40 + quad * 8];
    for (int mi = 0; mi < 4; mi++)
      for (int ni = 0; ni < 4; ni++)
        acc[mi][ni] = __builtin_amdgcn_mfma_f32_16x16x32_bf16(
            af[mi], bfv[ni], acc[mi][ni], 0, 0, 0);
  }
  for (int mi = 0; mi < 4; mi++)
    for (int ni = 0; ni < 4; ni++)
      for (int r = 0; r < 4; r++) {
        int m = m0 + mblk + mi * 16 + quad * 4 + r;
        int n = n0 + nblk + ni * 16 + col;
        int wid = n >> 9, feat = n & 511;
        float bias = wid == 0 ? bq[feat] : wid == 1 ? bk[feat] : bv[feat];
        bf16 v = (bf16)(acc[mi][ni][r] + bias);
        int bidx = m >> 11, seq = m & 2047;
        int h = feat >> 6, d = feat & 63;
        if (wid == 2)
          vtws[((((bidx << 3) + h) << 6) + d) * 2048 + seq] = v;
        else {
          bf16* dst = wid == 0 ? qws : kws;
          dst[((((bidx << 3) + h) << 11) + seq) * 64 + d] = v;
        }
      }
}

// ---------------- Kernel C: flash attention with geo bias ----------------
// one block = (b,h, 64-row Q tile); 4 waves, each wave owns 16 Q rows
__global__ __launch_bounds__(256) void attn_kernel(
    const bf16* __restrict__ qws, const bf16* __restrict__ kws,
    const bf16* __restrict__ vtws, const float* __restrict__ gbias,
    bf16* __restrict__ attn) {
  __shared__ bf16 Kl[64 * 72];  // [key][d]   stride 72 -> 144B rows
  __shared__ bf16 Vl[64 * 72];  // [d][key]
  __shared__ bf16 Pl[64 * 72];  // [qrow][key]
  int t = threadIdx.x, lane = t & 63, w = t >> 6;
  int quad = lane >> 4, col = lane & 15;
  int bh = blockIdx.x >> 5, qt = blockIdx.x & 31;
  int q0 = qt << 6;
  const bf16* qbase = qws + (size_t)bh * 2048 * 64;
  const bf16* kbase = kws + (size_t)bh * 2048 * 64;
  const bf16* vbase = vtws + (size_t)bh * 64 * 2048;
  const float* bb = gbias + ((size_t)bh * 2048 + q0) * 2048;

  bf16x8 aq[2];
  for (int ks = 0; ks < 2; ++ks)
    aq[ks] = *(const bf16x8*)&qbase[(q0 + w * 16 + col) * 64 + ks * 32 + quad * 8];

  f32x4 o[4] = {};
  float mrow[4], lrow[4];
  for (int r = 0; r < 4; r++) { mrow[r] = -INFINITY; lrow[r] = 0.f; }

  for (int kt = 0; kt < 32; ++kt) {
    int s0 = kt << 6;
    __syncthreads();
    for (int pass = 0; pass < 2; ++pass) {
      int c = t + (pass << 8);
      int row = c >> 3, part = c & 7;
      *(uint4*)&Kl[row * 72 + part * 8] =
          *(const uint4*)&kbase[(s0 + row) * 64 + part * 8];
      *(uint4*)&Vl[row * 72 + part * 8] =
          *(const uint4*)&vbase[row * 2048 + s0 + part * 8];
    }
    __syncthreads();
    // S = Q K^T (per wave: 16 rows x 64 keys)
    f32x4 s[4];
    for (int nt = 0; nt < 4; ++nt) {
      f32x4 a = {};
      for (int ks = 0; ks < 2; ++ks) {
        bf16x8 bk_ = *(const bf16x8*)&Kl[(nt * 16 + col) * 72 + ks * 32 + quad * 8];
        a = __builtin_amdgcn_mfma_f32_16x16x32_bf16(aq[ks], bk_, a, 0, 0, 0);
      }
      s[nt] = a;
    }
    // bias + online softmax, entirely in C-register layout
    float p[4][4];
    for (int r = 0; r < 4; r++) {
      int gq = w * 16 + quad * 4 + r;
      const float* brow = bb + (size_t)gq * 2048 + s0;
      float sv[4];
      float mx = -INFINITY;
      for (int nt = 0; nt < 4; nt++) {
        sv[nt] = s[nt][r] * SCALE + brow[nt * 16 + col];
        mx = fmaxf(mx, sv[nt]);
      }
      for (int d = 1; d < 16; d <<= 1) mx = fmaxf(mx, __shfl_xor(mx, d));
      float mnew = fmaxf(mrow[r], mx);
      float alpha = __expf(mrow[r] - mnew);
      float sum = 0.f;
      for (int nt = 0; nt < 4; nt++) {
        float e = __expf(sv[nt] - mnew);
        p[nt][r] = e; sum += e;
      }
      for (int d = 1; d < 16; d <<= 1) sum += __shfl_xor(sum, d);
      lrow[r] = lrow[r] * alpha + sum;
      mrow[r] = mnew;
      for (int dt = 0; dt < 4; ++dt) o[dt][r] *= alpha;
    }
    // P -> LDS (A-operand layout for PV)
    for (int nt = 0; nt < 4; nt++)
      for (int r = 0; r < 4; r++)
        Pl[(w * 16 + quad * 4 + r) * 72 + nt * 16 + col] = (bf16)p[nt][r];
    __syncthreads();
    // O += P V
    for (int ks = 0; ks < 2; ++ks) {
      bf16x8 ap = *(const bf16x8*)&Pl[(w * 16 + col) * 72 + ks * 32 + quad * 8];
      for (int dt = 0; dt < 4; ++dt) {
        bf16x8 bv_ = *(const bf16x8*)&Vl[(dt * 16 + col) * 72 + ks * 32 + quad * 8];
        o[dt] = __builtin_amdgcn_mfma_f32_16x16x32_bf16(ap, bv_, o[dt], 0, 0, 0);
      }
    }
  }
  // finalize: divide by l, store [b][seq][h*64+d] bf16
  bf16* obase = attn + (size_t)(bh >> 3) * 2048 * 512 + (bh & 7) * 64;
  for (int r = 0; r < 4; r++) {
    float inv = 1.f / lrow[r];
    int gq = q0 + w * 16 + quad * 4 + r;
    for (int dt = 0; dt < 4; ++dt)
      obase[(size_t)gq * 512 + dt * 16 + col] = (bf16)(o[dt][r] * inv);
  }
}

// ---------------- Kernel D: output projection ----------------
__global__ __launch_bounds__(256) void out_gemm(
    const bf16* __restrict__ ab, const bf16* __restrict__ wob,
    const float* __restrict__ bo, float* __restrict__ out) {
  __shared__ bf16 Al[128 * 40];
  __shared__ bf16 Bl[128 * 40];
  int t = threadIdx.x;
  int m0 = (blockIdx.x & 31) << 7;
  int n0 = (blockIdx.x >> 5) << 7;
  int lane = t & 63, w = t >> 6;
  int quad = lane >> 4, col = lane & 15;
  int mblk = (w >> 1) * 64, nblk = (w & 1) * 64;
  f32x4 acc[4][4] = {};
  for (int k0 = 0; k0 < 512; k0 += 32) {
    __syncthreads();
    for (int pass = 0; pass < 2; ++pass) {
      int c = t + (pass << 8);
      int row = c >> 2, part = c & 3;
      *(uint4*)&Al[row * 40 + part * 8] =
          *(const uint4*)&ab[(m0 + row) * 512 + k0 + part * 8];
      *(uint4*)&Bl[row * 40 + part * 8] =
          *(const uint4*)&wob[(n0 + row) * 512 + k0 + part * 8];
    }
    __syncthreads();
    bf16x8 af[4], bfv[4];
    for (int i = 0; i < 4; i++)
      af[i] = *(const bf16x8*)&Al[(mblk + i * 16 + col) * 40 + quad * 8];
    for (int i = 0; i < 4; i++)
      bfv[i] = *(const bf16x8*)&Bl[(nblk + i * 16 + col) * 40 + quad * 8];
    for (int mi = 0; mi < 4; mi++)
      for (int ni = 0; ni < 4; ni++)
        acc[mi][ni] = __builtin_amdgcn_mfma_f32_16x16x32_bf16(
            af[mi], bfv[ni], acc[mi][ni], 0, 0, 0);
  }
  for (int mi = 0; mi < 4; mi++)
    for (int ni = 0; ni < 4; ni++)
      for (int r = 0; r < 4; r++) {
        int m = m0 + mblk + mi * 16 + quad * 4 + r;
        int n = n0 + nblk + ni * 16 + col;
        out[(size_t)m * 512 + n] = acc[mi][ni][r] + bo[n];
      }
}

extern "C" void kernel_launch(void* const* d_in, const int* in_sizes, int n_in,
                              void* d_out, int out_size, void* d_ws, size_t ws_size,
                              hipStream_t stream) {
  const float* x  = (const float*)d_in[0];
  const float* gb = (const float*)d_in[1];
  const float* Wq = (const float*)d_in[2];
  const float* bq = (const float*)d_in[3];
  const float* Wk = (const float*)d_in[4];
  const float* bk = (const float*)d_in[5];
  const float* Wv = (const float*)d_in[6];
  const float* bv = (const float*)d_in[7];
  const float* Wo = (const float*)d_in[8];
  const float* bo = (const float*)d_in[9];
  float* out = (float*)d_out;
  char* ws = (char*)d_ws;
  bf16* xb   = (bf16*)(ws + WS_XB);
  bf16* wb   = (bf16*)(ws + WS_WB);
  bf16* qws  = (bf16*)(ws + WS_Q);
  bf16* kws  = (bf16*)(ws + WS_K);
  bf16* vtws = (bf16*)(ws + WS_VT);
  bf16* at   = (bf16*)(ws + WS_AT);

  hipLaunchKernelGGL(convert_kernel, dim3(3072), dim3(256), 0, stream,
                     x, Wq, Wk, Wv, Wo, xb, wb);
  hipLaunchKernelGGL(qkv_gemm, dim3(384), dim3(256), 0, stream,
                     xb, wb, bq, bk, bv, qws, kws, vtws);
  hipLaunchKernelGGL(attn_kernel, dim3(512), dim3(256), 0, stream,
                     qws, kws, vtws, gb, at);
  hipLaunchKernelGGL(out_gemm, dim3(128), dim3(256), 0, stream,
                     at, wb + 3 * 262144, bo, out);
}

// Round 2
// 440.225 us; speedup vs baseline: 1.0106x; 1.0106x over previous
//
#include <hip/hip_runtime.h>
#include <math.h>

#define SCALE 0.125f

typedef __bf16 bf16;
typedef __bf16 bf16x8 __attribute__((ext_vector_type(8)));
typedef float f32x4 __attribute__((ext_vector_type(4)));

// workspace byte offsets
#define WS_XB   0u            // x bf16:   4096*512*2          = 4 MB
#define WS_WB   4194304u      // Wq,Wk,Wv,Wo bf16: 4*512*512*2 = 2 MB
#define WS_Q    6291456u      // q  [b][h][n][d] bf16          = 4 MB
#define WS_K    10485760u     // k  [b][h][n][d] bf16          = 4 MB
#define WS_VT   14680064u     // vT [b][h][d][n] bf16          = 4 MB
#define WS_AT   18874368u     // attn out [b][n][h*64+d] bf16  = 4 MB

// ---------------- Kernel A: fp32 -> bf16 pack ----------------
__global__ __launch_bounds__(256) void convert_kernel(
    const float* __restrict__ x, const float* __restrict__ wq,
    const float* __restrict__ wk, const float* __restrict__ wv,
    const float* __restrict__ wo, bf16* __restrict__ xb, bf16* __restrict__ wb) {
  int i = blockIdx.x * 256 + threadIdx.x;  // float4 index; total 786432
  const float4* src; bf16* dst; int off;
  if (i < 524288) { src = (const float4*)x; dst = xb; off = i; }
  else {
    int j = i - 524288;
    int wsel = j >> 16; off = j & 65535;
    const float* wl = wsel == 0 ? wq : wsel == 1 ? wk : wsel == 2 ? wv : wo;
    src = (const float4*)wl; dst = wb + (wsel << 18);
  }
  float4 v = src[off];
  union { bf16 h[4]; uint2 u; } tmp;
  tmp.h[0] = (bf16)v.x; tmp.h[1] = (bf16)v.y;
  tmp.h[2] = (bf16)v.z; tmp.h[3] = (bf16)v.w;
  ((uint2*)dst)[off] = tmp.u;
}

// ---------------- Kernel B: QKV projection GEMM ----------------
__global__ __launch_bounds__(256) void qkv_gemm(
    const bf16* __restrict__ xb, const bf16* __restrict__ wb,
    const float* __restrict__ bq, const float* __restrict__ bk,
    const float* __restrict__ bv, bf16* __restrict__ qws,
    bf16* __restrict__ kws, bf16* __restrict__ vtws) {
  __shared__ bf16 Al[128 * 40];
  __shared__ bf16 Bl[128 * 40];
  int t = threadIdx.x;
  int m0 = (blockIdx.x & 31) << 7;
  int n0 = (blockIdx.x >> 5) << 7;
  int lane = t & 63, w = t >> 6;
  int quad = lane >> 4, col = lane & 15;
  int mblk = (w >> 1) * 64, nblk = (w & 1) * 64;
  f32x4 acc[4][4] = {};
  for (int k0 = 0; k0 < 512; k0 += 32) {
    __syncthreads();
    for (int pass = 0; pass < 2; ++pass) {
      int c = t + (pass << 8);
      int row = c >> 2, part = c & 3;
      *(uint4*)&Al[row * 40 + part * 8] =
          *(const uint4*)&xb[(m0 + row) * 512 + k0 + part * 8];
      *(uint4*)&Bl[row * 40 + part * 8] =
          *(const uint4*)&wb[(n0 + row) * 512 + k0 + part * 8];
    }
    __syncthreads();
    bf16x8 af[4], bfv[4];
    for (int i = 0; i < 4; i++)
      af[i] = *(const bf16x8*)&Al[(mblk + i * 16 + col) * 40 + quad * 8];
    for (int i = 0; i < 4; i++)
      bfv[i] = *(const bf16x8*)&Bl[(nblk + i * 16 + col) * 40 + quad * 8];
    for (int mi = 0; mi < 4; mi++)
      for (int ni = 0; ni < 4; ni++)
        acc[mi][ni] = __builtin_amdgcn_mfma_f32_16x16x32_bf16(
            af[mi], bfv[ni], acc[mi][ni], 0, 0, 0);
  }
  for (int mi = 0; mi < 4; mi++)
    for (int ni = 0; ni < 4; ni++) {
      int n = n0 + nblk + ni * 16 + col;
      int wid = n >> 9, feat = n & 511;
      float bias = wid == 0 ? bq[feat] : wid == 1 ? bk[feat] : bv[feat];
      int h = feat >> 6, d = feat & 63;
      int mbase = m0 + mblk + mi * 16 + quad * 4;
      int bidx = mbase >> 11, seq0 = mbase & 2047;
      if (wid == 2) {
        // pack 4 consecutive seq into one 8B store (V^T layout [b][h][d][n])
        union { bf16 h4[4]; ushort4 u4; } pk;
        for (int r = 0; r < 4; r++) pk.h4[r] = (bf16)(acc[mi][ni][r] + bias);
        *(ushort4*)&vtws[(size_t)((((bidx << 3) + h) << 6) + d) * 2048 + seq0] = pk.u4;
      } else {
        bf16* dst = wid == 0 ? qws : kws;
        for (int r = 0; r < 4; r++)
          dst[(size_t)((((bidx << 3) + h) << 11) + seq0 + r) * 64 + d] =
              (bf16)(acc[mi][ni][r] + bias);
      }
    }
}

// ---------------- Kernel C: flash attention with geo bias ----------------
// one block = (b,h, 64-row Q tile); 4 waves, each wave owns 16 Q rows.
// K/V LDS double-buffered (1 barrier/iter); bias register-prefetched ~2 tiles ahead.
__global__ __launch_bounds__(256, 2) void attn_kernel(
    const bf16* __restrict__ qws, const bf16* __restrict__ kws,
    const bf16* __restrict__ vtws, const float* __restrict__ gbias,
    bf16* __restrict__ attn) {
  __shared__ bf16 Kl[2][64 * 72];  // [buf][key][d]
  __shared__ bf16 Vl[2][64 * 72];  // [buf][d][key]
  __shared__ bf16 Pl[64 * 72];     // [qrow][key] (wave-private rows)
  int t = threadIdx.x, lane = t & 63, w = t >> 6;
  int quad = lane >> 4, col = lane & 15;
  int bh = blockIdx.x >> 5, qt = blockIdx.x & 31;
  int q0 = qt << 6;
  const bf16* qbase = qws + (size_t)bh * 2048 * 64;
  const bf16* kbase = kws + (size_t)bh * 2048 * 64;
  const bf16* vbase = vtws + (size_t)bh * 64 * 2048;
  const float* bb = gbias + ((size_t)bh * 2048 + q0) * 2048;

  // staging: 4 threads per row, 16 bf16 (2 x uint4) each
  int srow = t >> 2;
  int scol = (t & 3) << 4;

  // Q fragments (A-operand), per wave: rows w*16..w*16+15
  bf16x8 aq[2];
  for (int ks = 0; ks < 2; ++ks)
    aq[ks] = *(const bf16x8*)&qbase[(q0 + w * 16 + col) * 64 + ks * 32 + quad * 8];

  f32x4 o[4] = {};
  float mrow[4], lrow[4];
  for (int r = 0; r < 4; r++) { mrow[r] = -INFINITY; lrow[r] = 0.f; }

  // bias prefetch registers: bc[buf][r*4+nt]
  float bc[2][16];
  for (int r = 0; r < 4; r++)
    for (int nt = 0; nt < 4; nt++) {
      const float* brow = bb + (size_t)(w * 16 + quad * 4 + r) * 2048;
      bc[0][r * 4 + nt] = brow[nt * 16 + col];
      bc[1][r * 4 + nt] = brow[64 + nt * 16 + col];
    }

  // prologue: stage K/V tile 0 into buf 0
  {
    *(uint4*)&Kl[0][srow * 72 + scol]     = *(const uint4*)&kbase[srow * 64 + scol];
    *(uint4*)&Kl[0][srow * 72 + scol + 8] = *(const uint4*)&kbase[srow * 64 + scol + 8];
    *(uint4*)&Vl[0][srow * 72 + scol]     = *(const uint4*)&vbase[srow * 2048 + scol];
    *(uint4*)&Vl[0][srow * 72 + scol + 8] = *(const uint4*)&vbase[srow * 2048 + scol + 8];
  }
  __syncthreads();

  for (int kt = 0; kt < 32; kt += 2) {
#pragma unroll
    for (int u = 0; u < 2; ++u) {
      const int cur = u;  // constant after unroll -> bc[cur] stays in regs
      int kt_ = kt + u;
      int snxt = (kt_ + 1) << 6;  // may run past tile 31: lands in adjacent ws, unused

      // issue next K/V tile loads (global -> regs), no wait yet
      uint4 kra = *(const uint4*)&kbase[(snxt + srow) * 64 + scol];
      uint4 krb = *(const uint4*)&kbase[(snxt + srow) * 64 + scol + 8];
      uint4 vra = *(const uint4*)&vbase[srow * 2048 + snxt + scol];
      uint4 vrb = *(const uint4*)&vbase[srow * 2048 + snxt + scol + 8];

      // S = Q K^T from current LDS buffer
      f32x4 s[4];
#pragma unroll
      for (int nt = 0; nt < 4; ++nt) {
        f32x4 a = {};
#pragma unroll
        for (int ks = 0; ks < 2; ++ks) {
          bf16x8 bk_ = *(const bf16x8*)&Kl[cur][(nt * 16 + col) * 72 + ks * 32 + quad * 8];
          a = __builtin_amdgcn_mfma_f32_16x16x32_bf16(aq[ks], bk_, a, 0, 0, 0);
        }
        s[nt] = a;
      }

      // online softmax in C-register layout, bias from prefetched regs
      float p[4][4];
#pragma unroll
      for (int r = 0; r < 4; r++) {
        float sv[4];
        float mx = -INFINITY;
#pragma unroll
        for (int nt = 0; nt < 4; nt++) {
          sv[nt] = s[nt][r] * SCALE + bc[cur][r * 4 + nt];
          mx = fmaxf(mx, sv[nt]);
        }
#pragma unroll
        for (int d = 1; d < 16; d <<= 1) mx = fmaxf(mx, __shfl_xor(mx, d));
        float mnew = fmaxf(mrow[r], mx);
        float alpha = __expf(mrow[r] - mnew);
        float sum = 0.f;
#pragma unroll
        for (int nt = 0; nt < 4; nt++) {
          float e = __expf(sv[nt] - mnew);
          p[nt][r] = e; sum += e;
        }
#pragma unroll
        for (int d = 1; d < 16; d <<= 1) sum += __shfl_xor(sum, d);
        lrow[r] = lrow[r] * alpha + sum;
        mrow[r] = mnew;
#pragma unroll
        for (int dt = 0; dt < 4; ++dt) o[dt][r] *= alpha;
      }

      // bias regs for tile kt_+2 (consume-then-refill: ~1.5-2 iter prefetch depth)
      if (kt_ < 30) {
        int sb = (kt_ + 2) << 6;
#pragma unroll
        for (int r = 0; r < 4; r++) {
          const float* brow = bb + (size_t)(w * 16 + quad * 4 + r) * 2048 + sb;
#pragma unroll
          for (int nt = 0; nt < 4; nt++)
            bc[cur][r * 4 + nt] = brow[nt * 16 + col];
        }
      }

      // P -> LDS (wave-private rows; no block barrier needed, only lgkmcnt)
#pragma unroll
      for (int nt = 0; nt < 4; nt++)
#pragma unroll
        for (int r = 0; r < 4; r++)
          Pl[(w * 16 + quad * 4 + r) * 72 + nt * 16 + col] = (bf16)p[nt][r];

      // O += P V from current buffer
#pragma unroll
      for (int ks = 0; ks < 2; ++ks) {
        bf16x8 ap = *(const bf16x8*)&Pl[(w * 16 + col) * 72 + ks * 32 + quad * 8];
#pragma unroll
        for (int dt = 0; dt < 4; ++dt) {
          bf16x8 bv_ = *(const bf16x8*)&Vl[cur][(dt * 16 + col) * 72 + ks * 32 + quad * 8];
          o[dt] = __builtin_amdgcn_mfma_f32_16x16x32_bf16(ap, bv_, o[dt], 0, 0, 0);
        }
      }

      // stage next K/V into the other buffer (vmcnt waits via reg dependency)
      int nb = 1 - cur;
      *(uint4*)&Kl[nb][srow * 72 + scol]     = kra;
      *(uint4*)&Kl[nb][srow * 72 + scol + 8] = krb;
      *(uint4*)&Vl[nb][srow * 72 + scol]     = vra;
      *(uint4*)&Vl[nb][srow * 72 + scol + 8] = vrb;
      __syncthreads();
    }
  }

  // finalize: divide by l, store [b][seq][h*64+d] bf16
  bf16* obase = attn + (size_t)(bh >> 3) * 2048 * 512 + (bh & 7) * 64;
  for (int r = 0; r < 4; r++) {
    float inv = 1.f / lrow[r];
    int gq = q0 + w * 16 + quad * 4 + r;
    for (int dt = 0; dt < 4; ++dt)
      obase[(size_t)gq * 512 + dt * 16 + col] = (bf16)(o[dt][r] * inv);
  }
}

// ---------------- Kernel D: output projection ----------------
__global__ __launch_bounds__(256) void out_gemm(
    const bf16* __restrict__ ab, const bf16* __restrict__ wob,
    const float* __restrict__ bo, float* __restrict__ out) {
  __shared__ bf16 Al[128 * 40];
  __shared__ bf16 Bl[128 * 40];
  int t = threadIdx.x;
  int m0 = (blockIdx.x & 31) << 7;
  int n0 = (blockIdx.x >> 5) << 7;
  int lane = t & 63, w = t >> 6;
  int quad = lane >> 4, col = lane & 15;
  int mblk = (w >> 1) * 64, nblk = (w & 1) * 64;
  f32x4 acc[4][4] = {};
  for (int k0 = 0; k0 < 512; k0 += 32) {
    __syncthreads();
    for (int pass = 0; pass < 2; ++pass) {
      int c = t + (pass << 8);
      int row = c >> 2, part = c & 3;
      *(uint4*)&Al[row * 40 + part * 8] =
          *(const uint4*)&ab[(m0 + row) * 512 + k0 + part * 8];
      *(uint4*)&Bl[row * 40 + part * 8] =
          *(const uint4*)&wob[(n0 + row) * 512 + k0 + part * 8];
    }
    __syncthreads();
    bf16x8 af[4], bfv[4];
    for (int i = 0; i < 4; i++)
      af[i] = *(const bf16x8*)&Al[(mblk + i * 16 + col) * 40 + quad * 8];
    for (int i = 0; i < 4; i++)
      bfv[i] = *(const bf16x8*)&Bl[(nblk + i * 16 + col) * 40 + quad * 8];
    for (int mi = 0; mi < 4; mi++)
      for (int ni = 0; ni < 4; ni++)
        acc[mi][ni] = __builtin_amdgcn_mfma_f32_16x16x32_bf16(
            af[mi], bfv[ni], acc[mi][ni], 0, 0, 0);
  }
  for (int mi = 0; mi < 4; mi++)
    for (int ni = 0; ni < 4; ni++)
      for (int r = 0; r < 4; r++) {
        int m = m0 + mblk + mi * 16 + quad * 4 + r;
        int n = n0 + nblk + ni * 16 + col;
        out[(size_t)m * 512 + n] = acc[mi][ni][r] + bo[n];
      }
}

extern "C" void kernel_launch(void* const* d_in, const int* in_sizes, int n_in,
                              void* d_out, int out_size, void* d_ws, size_t ws_size,
                              hipStream_t stream) {
  const float* x  = (const float*)d_in[0];
  const float* gb = (const float*)d_in[1];
  const float* Wq = (const float*)d_in[2];
  const float* bq = (const float*)d_in[3];
  const float* Wk = (const float*)d_in[4];
  const float* bk = (const float*)d_in[5];
  const float* Wv = (const float*)d_in[6];
  const float* bv = (const float*)d_in[7];
  const float* Wo = (const float*)d_in[8];
  const float* bo = (const float*)d_in[9];
  float* out = (float*)d_out;
  char* ws = (char*)d_ws;
  bf16* xb   = (bf16*)(ws + WS_XB);
  bf16* wb   = (bf16*)(ws + WS_WB);
  bf16* qws  = (bf16*)(ws + WS_Q);
  bf16* kws  = (bf16*)(ws + WS_K);
  bf16* vtws = (bf16*)(ws + WS_VT);
  bf16* at   = (bf16*)(ws + WS_AT);

  hipLaunchKernelGGL(convert_kernel, dim3(3072), dim3(256), 0, stream,
                     x, Wq, Wk, Wv, Wo, xb, wb);
  hipLaunchKernelGGL(qkv_gemm, dim3(384), dim3(256), 0, stream,
                     xb, wb, bq, bk, bv, qws, kws, vtws);
  hipLaunchKernelGGL(attn_kernel, dim3(512), dim3(256), 0, stream,
                     qws, kws, vtws, gb, at);
  hipLaunchKernelGGL(out_gemm, dim3(128), dim3(256), 0, stream,
                     at, wb + 3 * 262144, bo, out);
}